// Round 4
// baseline (147.687 us; speedup 1.0000x reference)
//
#include <hip/hip_runtime.h>
#include <math.h>

typedef __attribute__((ext_vector_type(8))) _Float16 f16x8;
typedef __attribute__((ext_vector_type(4))) float f32x4;

#define BT 8192     // T rows per batch
#define BS 200      // S cols per batch
#define SP 208      // S padded to multiple of 16
#define DD 256      // D
#define NJ 13       // S tiles of 16
#define NKB 8       // k blocks of 32

// ws layout (units of _Float16 halves unless noted):
//   hi plane: [8 b][NKB][NJ] slots of 512 halves (64 lanes x 8)
//   lo plane: same, offset PLANE_H
//   norms:    float [8][SP] after both planes
#define SLOT_H 512
#define PLANE_SLOTS (8 * NKB * NJ)          // 832
#define PLANE_H ((size_t)PLANE_SLOTS * SLOT_H)
#define WS_NEED (2 * PLANE_H * 2 + 8 * SP * 4)  // 1,710,592 bytes

// ---------------- pre-pass: spk f32 -> fragment-layout f16 hi/lo + norms ----
__global__ __launch_bounds__(256, 4)
void spk_prep_kernel(const float* __restrict__ SPK, _Float16* __restrict__ wsH) {
    const int j = blockIdx.x;          // 0..12
    const int b = blockIdx.y;          // 0..7
    const int tid = threadIdx.x;
    const int w = tid >> 6;            // wave 0..3 handles kb = w, w+4
    const int lane = tid & 63;
    const int lr = lane & 15;          // spk row within tile (= B col)
    const int lg = lane >> 4;          // k-group
    const int srow = j * 16 + lr;
    const float* __restrict__ spk_b = SPK + (size_t)b * BS * DD;

    __shared__ float pn[4][16];
    float ss = 0.f;

    #pragma unroll
    for (int t = 0; t < 2; ++t) {
        int kb = w + t * 4;
        f16x8 hi, lo;
        if (srow < BS) {
            const float* src = spk_b + srow * DD + kb * 32 + lg * 8;
            float4 v0 = *(const float4*)src;
            float4 v1 = *(const float4*)(src + 4);
            float xv[8] = {v0.x, v0.y, v0.z, v0.w, v1.x, v1.y, v1.z, v1.w};
            #pragma unroll
            for (int e = 0; e < 8; ++e) {
                _Float16 h = (_Float16)xv[e];
                hi[e] = h;
                lo[e] = (_Float16)(xv[e] - (float)h);
                ss = fmaf(xv[e], xv[e], ss);
            }
        } else {
            #pragma unroll
            for (int e = 0; e < 8; ++e) { hi[e] = (_Float16)0.f; lo[e] = (_Float16)0.f; }
        }
        size_t slot = ((size_t)(b * NKB + kb) * NJ + j) * SLOT_H + lane * 8;
        *(f16x8*)&wsH[slot] = hi;
        *(f16x8*)&wsH[PLANE_H + slot] = lo;
    }

    // row sum-of-squares: each wave covered 64 k-values of row (j*16+lr)
    ss += __shfl_xor(ss, 16, 64);
    ss += __shfl_xor(ss, 32, 64);
    if (lane < 16) pn[w][lane] = ss;
    __syncthreads();
    if (tid < 16) {
        float s = pn[0][tid] + pn[1][tid] + pn[2][tid] + pn[3][tid];
        float* sn = (float*)(wsH + 2 * PLANE_H);
        sn[b * SP + j * 16 + tid] = sqrtf(s);
    }
}

// ---------------- main: barrier-free, LDS-free MFMA ------------------------
__global__ __launch_bounds__(256, 4)
void cos_main_kernel(const float* __restrict__ X, const _Float16* __restrict__ wsH,
                     float* __restrict__ OUT) {
    const int b   = blockIdx.y;
    const int t0  = blockIdx.x * 64;          // 4 waves x 16 rows
    const int tid = threadIdx.x;
    const int wid = tid >> 6;
    const int lane = tid & 63;
    const int lr = lane & 15;
    const int lg = lane >> 4;

    const float* __restrict__ xrow = X + ((size_t)b * BT + t0 + wid * 16 + lr) * DD;
    const float* __restrict__ snW = (const float*)(wsH + 2 * PLANE_H) + b * SP;

    float4 pa0 = *(const float4*)(xrow + lg * 8);
    float4 pa1 = *(const float4*)(xrow + lg * 8 + 4);

    f32x4 acc[NJ];
    #pragma unroll
    for (int j = 0; j < NJ; ++j) acc[j] = (f32x4){0.f, 0.f, 0.f, 0.f};
    float ss = 0.f;

    for (int kb = 0; kb < NKB; ++kb) {
        f16x8 ahi, alo;
        {
            float xv[8] = {pa0.x, pa0.y, pa0.z, pa0.w, pa1.x, pa1.y, pa1.z, pa1.w};
            #pragma unroll
            for (int e = 0; e < 8; ++e) {
                _Float16 h = (_Float16)xv[e];
                ahi[e] = h;
                alo[e] = (_Float16)(xv[e] - (float)h);
                ss = fmaf(xv[e], xv[e], ss);
            }
        }
        if (kb < NKB - 1) {
            int o = (kb + 1) * 32 + lg * 8;
            pa0 = *(const float4*)(xrow + o);
            pa1 = *(const float4*)(xrow + o + 4);
        }
        const _Float16* __restrict__ base =
            wsH + ((size_t)(b * NKB + kb) * NJ) * SLOT_H + lane * 8;
        #pragma unroll
        for (int j = 0; j < NJ; ++j) {
            f16x8 bhi = *(const f16x8*)(base + (size_t)j * SLOT_H);
            f16x8 blo = *(const f16x8*)(base + PLANE_H + (size_t)j * SLOT_H);
            acc[j] = __builtin_amdgcn_mfma_f32_16x16x32_f16(ahi, bhi, acc[j], 0, 0, 0);
            acc[j] = __builtin_amdgcn_mfma_f32_16x16x32_f16(alo, bhi, acc[j], 0, 0, 0);
            acc[j] = __builtin_amdgcn_mfma_f32_16x16x32_f16(ahi, blo, acc[j], 0, 0, 0);
        }
    }

    ss += __shfl_xor(ss, 16, 64);
    ss += __shfl_xor(ss, 32, 64);

    #pragma unroll
    for (int reg = 0; reg < 4; ++reg) {
        int rc = lg * 4 + reg;                    // C/D row = (lane>>4)*4+reg (m89)
        float xn = sqrtf(__shfl(ss, rc, 64));
        int row = t0 + wid * 16 + rc;
        float* orow = OUT + ((size_t)b * BT + row) * BS;
        #pragma unroll
        for (int j = 0; j < NJ; ++j) {
            int col = j * 16 + lr;                // C/D col = lane&15
            if (col < BS) {
                float denom = fmaxf(xn * snW[col], 1e-8f);
                orow[col] = acc[j][reg] * __builtin_amdgcn_rcpf(denom);
            }
        }
    }
}

// ---------------- fallback (round-3 proven kernel, used if ws too small) ----
#define TM 128
#define LSTR 40

__global__ __launch_bounds__(256, 2)
void cos_scorer_kernel(const float* __restrict__ X, const float* __restrict__ SPK,
                       float* __restrict__ OUT) {
    const int b   = blockIdx.y;
    const int t0  = blockIdx.x * TM;
    const int tid = threadIdx.x;
    const int wid = tid >> 6;
    const int lane = tid & 63;
    const int lr  = lane & 15;
    const int lg  = lane >> 4;

    __shared__ _Float16 Shi[SP * LSTR];
    __shared__ _Float16 Slo[SP * LSTR];
    __shared__ float sn_l[SP];

    const float* __restrict__ spk_b = SPK + (size_t)b * BS * DD;
    const float* __restrict__ xrow0 = X + ((size_t)b * BT + t0 + wid * 32 + lr) * DD;
    const float* __restrict__ xrow1 = xrow0 + 16 * DD;

    float4 pa00 = *(const float4*)(xrow0 + lg * 8);
    float4 pa01 = *(const float4*)(xrow0 + lg * 8 + 4);
    float4 pa10 = *(const float4*)(xrow1 + lg * 8);
    float4 pa11 = *(const float4*)(xrow1 + lg * 8 + 4);

    if (tid < SP) {
        float ss = 0.f;
        if (tid < BS) {
            const float4* p = (const float4*)(spk_b + tid * DD);
            #pragma unroll 8
            for (int i = 0; i < DD / 4; ++i) {
                float4 v = p[i];
                ss = fmaf(v.x, v.x, ss); ss = fmaf(v.y, v.y, ss);
                ss = fmaf(v.z, v.z, ss); ss = fmaf(v.w, v.w, ss);
            }
        }
        sn_l[tid] = sqrtf(ss);
    }

    f32x4 acc[2][NJ];
    #pragma unroll
    for (int rt = 0; rt < 2; ++rt)
        #pragma unroll
        for (int j = 0; j < NJ; ++j)
            acc[rt][j] = (f32x4){0.f, 0.f, 0.f, 0.f};

    float ss0 = 0.f, ss1 = 0.f;

    for (int kb = 0; kb < 8; ++kb) {
        for (int i = tid; i < SP * 4; i += 256) {
            int s = i >> 2, part = i & 3;
            f16x8 hi, lo;
            #pragma unroll
            for (int e = 0; e < 8; ++e) { hi[e] = (_Float16)0.f; lo[e] = (_Float16)0.f; }
            if (s < BS) {
                const float* src = spk_b + s * DD + kb * 32 + part * 8;
                float4 v0 = *(const float4*)src;
                float4 v1 = *(const float4*)(src + 4);
                float xv[8] = {v0.x, v0.y, v0.z, v0.w, v1.x, v1.y, v1.z, v1.w};
                #pragma unroll
                for (int e = 0; e < 8; ++e) {
                    _Float16 h = (_Float16)xv[e];
                    hi[e] = h;
                    lo[e] = (_Float16)(xv[e] - (float)h);
                }
            }
            int off = s * LSTR + part * 8;
            *(f16x8*)&Shi[off] = hi;
            *(f16x8*)&Slo[off] = lo;
        }
        __syncthreads();

        f16x8 ahi0, alo0, ahi1, alo1;
        {
            float xv0[8] = {pa00.x, pa00.y, pa00.z, pa00.w, pa01.x, pa01.y, pa01.z, pa01.w};
            float xv1[8] = {pa10.x, pa10.y, pa10.z, pa10.w, pa11.x, pa11.y, pa11.z, pa11.w};
            #pragma unroll
            for (int e = 0; e < 8; ++e) {
                _Float16 h0 = (_Float16)xv0[e];
                ahi0[e] = h0; alo0[e] = (_Float16)(xv0[e] - (float)h0);
                ss0 = fmaf(xv0[e], xv0[e], ss0);
                _Float16 h1 = (_Float16)xv1[e];
                ahi1[e] = h1; alo1[e] = (_Float16)(xv1[e] - (float)h1);
                ss1 = fmaf(xv1[e], xv1[e], ss1);
            }
        }
        if (kb < 7) {
            int o = (kb + 1) * 32 + lg * 8;
            pa00 = *(const float4*)(xrow0 + o);
            pa01 = *(const float4*)(xrow0 + o + 4);
            pa10 = *(const float4*)(xrow1 + o);
            pa11 = *(const float4*)(xrow1 + o + 4);
        }

        #pragma unroll
        for (int j = 0; j < NJ; ++j) {
            int boff = (j * 16 + lr) * LSTR + lg * 8;
            f16x8 bhi = *(const f16x8*)&Shi[boff];
            f16x8 blo = *(const f16x8*)&Slo[boff];
            acc[0][j] = __builtin_amdgcn_mfma_f32_16x16x32_f16(ahi0, bhi, acc[0][j], 0, 0, 0);
            acc[1][j] = __builtin_amdgcn_mfma_f32_16x16x32_f16(ahi1, bhi, acc[1][j], 0, 0, 0);
            acc[0][j] = __builtin_amdgcn_mfma_f32_16x16x32_f16(alo0, bhi, acc[0][j], 0, 0, 0);
            acc[1][j] = __builtin_amdgcn_mfma_f32_16x16x32_f16(alo1, bhi, acc[1][j], 0, 0, 0);
            acc[0][j] = __builtin_amdgcn_mfma_f32_16x16x32_f16(ahi0, blo, acc[0][j], 0, 0, 0);
            acc[1][j] = __builtin_amdgcn_mfma_f32_16x16x32_f16(ahi1, blo, acc[1][j], 0, 0, 0);
        }
        __syncthreads();
    }

    ss0 += __shfl_xor(ss0, 16, 64);
    ss0 += __shfl_xor(ss0, 32, 64);
    ss1 += __shfl_xor(ss1, 16, 64);
    ss1 += __shfl_xor(ss1, 32, 64);

    #pragma unroll
    for (int rt = 0; rt < 2; ++rt) {
        float ssv = rt ? ss1 : ss0;
        #pragma unroll
        for (int reg = 0; reg < 4; ++reg) {
            int rc = lg * 4 + reg;
            float xn = sqrtf(__shfl(ssv, rc, 64));
            int row = t0 + wid * 32 + rt * 16 + rc;
            float* orow = OUT + ((size_t)b * BT + row) * BS;
            #pragma unroll
            for (int j = 0; j < NJ; ++j) {
                int col = j * 16 + lr;
                if (col < BS) {
                    float denom = fmaxf(xn * sn_l[col], 1e-8f);
                    orow[col] = acc[rt][j][reg] * __builtin_amdgcn_rcpf(denom);
                }
            }
        }
    }
}

extern "C" void kernel_launch(void* const* d_in, const int* in_sizes, int n_in,
                              void* d_out, int out_size, void* d_ws, size_t ws_size,
                              hipStream_t stream) {
    const float* X   = (const float*)d_in[0];   // [8, 8192, 256] f32
    const float* SPK = (const float*)d_in[1];   // [8, 200, 256] f32
    float* OUT = (float*)d_out;                 // [8, 8192, 200] f32

    if (ws_size >= (size_t)WS_NEED) {
        _Float16* wsH = (_Float16*)d_ws;
        hipLaunchKernelGGL(spk_prep_kernel, dim3(NJ, 8), dim3(256), 0, stream, SPK, wsH);
        hipLaunchKernelGGL(cos_main_kernel, dim3(BT / 64, 8), dim3(256), 0, stream,
                           X, wsH, OUT);
    } else {
        hipLaunchKernelGGL(cos_scorer_kernel, dim3(BT / TM, 8), dim3(256), 0, stream,
                           X, SPK, OUT);
    }
}

// Round 7
// 122.437 us; speedup vs baseline: 1.2062x; 1.2062x over previous
//
#include <hip/hip_runtime.h>
#include <math.h>

typedef __attribute__((ext_vector_type(8))) _Float16 f16x8;
typedef __attribute__((ext_vector_type(4))) float f32x4;

#define BT 8192     // T rows per batch
#define BS 200      // S cols per batch
#define SP 208      // S padded
#define DD 256      // D
#define NJ 13       // S tiles of 16
#define NKB 8       // k blocks of 32
#define NSLOT 26    // 13 hi + 13 lo slots per (b,kb)
#define SLOT_H 512  // halves per slot (64 lanes x 8)
#define TOT_SLOTS (8 * NKB * NSLOT)                 // 1664
#define NORM_OFF ((size_t)TOT_SLOTS * SLOT_H)       // halves
#define WS_NEED (NORM_OFF * 2 + 8 * SP * 4)         // bytes

// generic->AS cast wrapper for direct global->LDS DMA (16B/lane, dest = base + lane*16)
__device__ __forceinline__ void gl_lds16(const _Float16* g, _Float16* l) {
    __builtin_amdgcn_global_load_lds(
        (const __attribute__((address_space(1))) unsigned int*)g,
        (__attribute__((address_space(3))) unsigned int*)l, 16, 0, 0);
}

// ---- pre-pass: spk f32 -> [b][kb][hi slots 0..12 | lo slots 13..25] + norms ----
__global__ __launch_bounds__(256, 4)
void spk_prep_kernel(const float* __restrict__ SPK, _Float16* __restrict__ wsH) {
    const int j = blockIdx.x;          // 0..12
    const int b = blockIdx.y;          // 0..7
    const int tid = threadIdx.x;
    const int w = tid >> 6;            // wave handles kb = w, w+4
    const int lane = tid & 63;
    const int lr = lane & 15;          // spk row within tile (= B col)
    const int lg = lane >> 4;          // k-group
    const int srow = j * 16 + lr;
    const float* __restrict__ spk_b = SPK + (size_t)b * BS * DD;

    __shared__ float pn[4][16];
    float ss = 0.f;

    #pragma unroll
    for (int t = 0; t < 2; ++t) {
        int kb = w + t * 4;
        f16x8 hi, lo;
        if (srow < BS) {
            const float* src = spk_b + srow * DD + kb * 32 + lg * 8;
            float4 v0 = *(const float4*)src;
            float4 v1 = *(const float4*)(src + 4);
            float xv[8] = {v0.x, v0.y, v0.z, v0.w, v1.x, v1.y, v1.z, v1.w};
            #pragma unroll
            for (int e = 0; e < 8; ++e) {
                _Float16 h = (_Float16)xv[e];
                hi[e] = h;
                lo[e] = (_Float16)(xv[e] - (float)h);
                ss = fmaf(xv[e], xv[e], ss);
            }
        } else {
            #pragma unroll
            for (int e = 0; e < 8; ++e) { hi[e] = (_Float16)0.f; lo[e] = (_Float16)0.f; }
        }
        size_t base = ((size_t)(b * NKB + kb) * NSLOT + j) * SLOT_H + lane * 8;
        *(f16x8*)&wsH[base] = hi;                        // hi slot j
        *(f16x8*)&wsH[base + 13 * SLOT_H] = lo;          // lo slot 13+j
    }

    ss += __shfl_xor(ss, 16, 64);
    ss += __shfl_xor(ss, 32, 64);
    if (lane < 16) pn[w][lane] = ss;
    __syncthreads();
    if (tid < 16) {
        float s = pn[0][tid] + pn[1][tid] + pn[2][tid] + pn[3][tid];
        float* sn = (float*)(wsH + NORM_OFF);
        sn[b * SP + j * 16 + tid] = sqrtf(s);
    }
}

// ---- main: LDS double-buffered B via global_load_lds, 2 row-tiles/wave --------
__global__ __launch_bounds__(256, 2)
void cos_main_kernel(const float* __restrict__ X, const _Float16* __restrict__ wsH,
                     float* __restrict__ OUT) {
    const int b   = blockIdx.y;
    const int t0  = blockIdx.x * 128;         // 4 waves x 32 rows
    const int tid = threadIdx.x;
    const int wid = tid >> 6;
    const int lane = tid & 63;
    const int lr = lane & 15;
    const int lg = lane >> 4;

    __shared__ _Float16 Bb[2][NSLOT * SLOT_H];   // 2 x 26 KB

    const float* __restrict__ xrow0 = X + ((size_t)b * BT + t0 + wid * 32 + lr) * DD;
    const float* __restrict__ xrow1 = xrow0 + 16 * DD;
    const float* __restrict__ snW = (const float*)(wsH + NORM_OFF) + b * SP;
    const _Float16* __restrict__ wsB = wsH + (size_t)b * NKB * NSLOT * SLOT_H;

    float4 pa00 = *(const float4*)(xrow0 + lg * 8);
    float4 pa01 = *(const float4*)(xrow0 + lg * 8 + 4);
    float4 pa10 = *(const float4*)(xrow1 + lg * 8);
    float4 pa11 = *(const float4*)(xrow1 + lg * 8 + 4);

    // prologue: stage kb=0 into buffer 0 (each wave takes slots wid, wid+4, ...)
    for (int s = wid; s < NSLOT; s += 4)
        gl_lds16(wsB + (size_t)s * SLOT_H + lane * 8, &Bb[0][s * SLOT_H]);
    __syncthreads();   // compiler drains vmcnt(0) here -> stage complete

    f32x4 acc[2][NJ];
    #pragma unroll
    for (int rt = 0; rt < 2; ++rt)
        #pragma unroll
        for (int j = 0; j < NJ; ++j)
            acc[rt][j] = (f32x4){0.f, 0.f, 0.f, 0.f};

    float ss0 = 0.f, ss1 = 0.f;
    int cur = 0;

    for (int kb = 0; kb < NKB; ++kb) {
        // issue next kb's B stage into the other buffer (in flight across MFMAs)
        if (kb < NKB - 1) {
            const _Float16* src = wsB + (size_t)(kb + 1) * NSLOT * SLOT_H;
            for (int s = wid; s < NSLOT; s += 4)
                gl_lds16(src + (size_t)s * SLOT_H + lane * 8, &Bb[cur ^ 1][s * SLOT_H]);
        }

        // convert current A regs -> hi/lo fragments, accumulate sumsq
        f16x8 ahi0, alo0, ahi1, alo1;
        {
            float xv0[8] = {pa00.x, pa00.y, pa00.z, pa00.w, pa01.x, pa01.y, pa01.z, pa01.w};
            float xv1[8] = {pa10.x, pa10.y, pa10.z, pa10.w, pa11.x, pa11.y, pa11.z, pa11.w};
            #pragma unroll
            for (int e = 0; e < 8; ++e) {
                _Float16 h0 = (_Float16)xv0[e];
                ahi0[e] = h0; alo0[e] = (_Float16)(xv0[e] - (float)h0);
                ss0 = fmaf(xv0[e], xv0[e], ss0);
                _Float16 h1 = (_Float16)xv1[e];
                ahi1[e] = h1; alo1[e] = (_Float16)(xv1[e] - (float)h1);
                ss1 = fmaf(xv1[e], xv1[e], ss1);
            }
        }
        // prefetch next kb's A f32
        if (kb < NKB - 1) {
            int o = (kb + 1) * 32 + lg * 8;
            pa00 = *(const float4*)(xrow0 + o);
            pa01 = *(const float4*)(xrow0 + o + 4);
            pa10 = *(const float4*)(xrow1 + o);
            pa11 = *(const float4*)(xrow1 + o + 4);
        }

        // MFMA over all S tiles from LDS (linear b128, conflict-free)
        const _Float16* __restrict__ bc = &Bb[cur][lane * 8];
        #pragma unroll
        for (int j = 0; j < NJ; ++j) {
            f16x8 bhi = *(const f16x8*)(bc + j * SLOT_H);
            f16x8 blo = *(const f16x8*)(bc + (13 + j) * SLOT_H);
            acc[0][j] = __builtin_amdgcn_mfma_f32_16x16x32_f16(ahi0, bhi, acc[0][j], 0, 0, 0);
            acc[1][j] = __builtin_amdgcn_mfma_f32_16x16x32_f16(ahi1, bhi, acc[1][j], 0, 0, 0);
            acc[0][j] = __builtin_amdgcn_mfma_f32_16x16x32_f16(alo0, bhi, acc[0][j], 0, 0, 0);
            acc[1][j] = __builtin_amdgcn_mfma_f32_16x16x32_f16(alo1, bhi, acc[1][j], 0, 0, 0);
            acc[0][j] = __builtin_amdgcn_mfma_f32_16x16x32_f16(ahi0, blo, acc[0][j], 0, 0, 0);
            acc[1][j] = __builtin_amdgcn_mfma_f32_16x16x32_f16(ahi1, blo, acc[1][j], 0, 0, 0);
        }

        if (kb < NKB - 1) {
            __syncthreads();   // drain (stage+prefetch) + barrier; swap buffers
            cur ^= 1;
        }
    }

    // ---- epilogue ----
    ss0 += __shfl_xor(ss0, 16, 64);
    ss0 += __shfl_xor(ss0, 32, 64);
    ss1 += __shfl_xor(ss1, 16, 64);
    ss1 += __shfl_xor(ss1, 32, 64);

    #pragma unroll
    for (int rt = 0; rt < 2; ++rt) {
        float ssv = rt ? ss1 : ss0;
        #pragma unroll
        for (int reg = 0; reg < 4; ++reg) {
            int rc = lg * 4 + reg;                 // C/D row = (lane>>4)*4+reg (m89)
            float xn = sqrtf(__shfl(ssv, rc, 64));
            int row = t0 + wid * 32 + rt * 16 + rc;
            float* orow = OUT + ((size_t)b * BT + row) * BS;
            #pragma unroll
            for (int j = 0; j < NJ; ++j) {
                int col = j * 16 + lr;             // C/D col = lane&15
                if (col < BS) {
                    float denom = fmaxf(xn * snW[col], 1e-8f);
                    orow[col] = acc[rt][j][reg] * __builtin_amdgcn_rcpf(denom);
                }
            }
        }
    }
}

// ---- fallback (round-3 proven kernel, used if ws too small) -------------------
#define TM 128
#define LSTR 40

__global__ __launch_bounds__(256, 2)
void cos_scorer_kernel(const float* __restrict__ X, const float* __restrict__ SPK,
                       float* __restrict__ OUT) {
    const int b   = blockIdx.y;
    const int t0  = blockIdx.x * TM;
    const int tid = threadIdx.x;
    const int wid = tid >> 6;
    const int lane = tid & 63;
    const int lr  = lane & 15;
    const int lg  = lane >> 4;

    __shared__ _Float16 Shi[SP * LSTR];
    __shared__ _Float16 Slo[SP * LSTR];
    __shared__ float sn_l[SP];

    const float* __restrict__ spk_b = SPK + (size_t)b * BS * DD;
    const float* __restrict__ xrow0 = X + ((size_t)b * BT + t0 + wid * 32 + lr) * DD;
    const float* __restrict__ xrow1 = xrow0 + 16 * DD;

    float4 pa00 = *(const float4*)(xrow0 + lg * 8);
    float4 pa01 = *(const float4*)(xrow0 + lg * 8 + 4);
    float4 pa10 = *(const float4*)(xrow1 + lg * 8);
    float4 pa11 = *(const float4*)(xrow1 + lg * 8 + 4);

    if (tid < SP) {
        float ss = 0.f;
        if (tid < BS) {
            const float4* p = (const float4*)(spk_b + tid * DD);
            #pragma unroll 8
            for (int i = 0; i < DD / 4; ++i) {
                float4 v = p[i];
                ss = fmaf(v.x, v.x, ss); ss = fmaf(v.y, v.y, ss);
                ss = fmaf(v.z, v.z, ss); ss = fmaf(v.w, v.w, ss);
            }
        }
        sn_l[tid] = sqrtf(ss);
    }

    f32x4 acc[2][NJ];
    #pragma unroll
    for (int rt = 0; rt < 2; ++rt)
        #pragma unroll
        for (int j = 0; j < NJ; ++j)
            acc[rt][j] = (f32x4){0.f, 0.f, 0.f, 0.f};

    float ss0 = 0.f, ss1 = 0.f;

    for (int kb = 0; kb < 8; ++kb) {
        for (int i = tid; i < SP * 4; i += 256) {
            int s = i >> 2, part = i & 3;
            f16x8 hi, lo;
            #pragma unroll
            for (int e = 0; e < 8; ++e) { hi[e] = (_Float16)0.f; lo[e] = (_Float16)0.f; }
            if (s < BS) {
                const float* src = spk_b + s * DD + kb * 32 + part * 8;
                float4 v0 = *(const float4*)src;
                float4 v1 = *(const float4*)(src + 4);
                float xv[8] = {v0.x, v0.y, v0.z, v0.w, v1.x, v1.y, v1.z, v1.w};
                #pragma unroll
                for (int e = 0; e < 8; ++e) {
                    _Float16 h = (_Float16)xv[e];
                    hi[e] = h;
                    lo[e] = (_Float16)(xv[e] - (float)h);
                }
            }
            int off = s * LSTR + part * 8;
            *(f16x8*)&Shi[off] = hi;
            *(f16x8*)&Slo[off] = lo;
        }
        __syncthreads();

        f16x8 ahi0, alo0, ahi1, alo1;
        {
            float xv0[8] = {pa00.x, pa00.y, pa00.z, pa00.w, pa01.x, pa01.y, pa01.z, pa01.w};
            float xv1[8] = {pa10.x, pa10.y, pa10.z, pa10.w, pa11.x, pa11.y, pa11.z, pa11.w};
            #pragma unroll
            for (int e = 0; e < 8; ++e) {
                _Float16 h0 = (_Float16)xv0[e];
                ahi0[e] = h0; alo0[e] = (_Float16)(xv0[e] - (float)h0);
                ss0 = fmaf(xv0[e], xv0[e], ss0);
                _Float16 h1 = (_Float16)xv1[e];
                ahi1[e] = h1; alo1[e] = (_Float16)(xv1[e] - (float)h1);
                ss1 = fmaf(xv1[e], xv1[e], ss1);
            }
        }
        if (kb < 7) {
            int o = (kb + 1) * 32 + lg * 8;
            pa00 = *(const float4*)(xrow0 + o);
            pa01 = *(const float4*)(xrow0 + o + 4);
            pa10 = *(const float4*)(xrow1 + o);
            pa11 = *(const float4*)(xrow1 + o + 4);
        }

        #pragma unroll
        for (int j = 0; j < NJ; ++j) {
            int boff = (j * 16 + lr) * LSTR + lg * 8;
            f16x8 bhi = *(const f16x8*)&Shi[boff];
            f16x8 blo = *(const f16x8*)&Slo[boff];
            acc[0][j] = __builtin_amdgcn_mfma_f32_16x16x32_f16(ahi0, bhi, acc[0][j], 0, 0, 0);
            acc[1][j] = __builtin_amdgcn_mfma_f32_16x16x32_f16(ahi1, bhi, acc[1][j], 0, 0, 0);
            acc[0][j] = __builtin_amdgcn_mfma_f32_16x16x32_f16(alo0, bhi, acc[0][j], 0, 0, 0);
            acc[1][j] = __builtin_amdgcn_mfma_f32_16x16x32_f16(alo1, bhi, acc[1][j], 0, 0, 0);
            acc[0][j] = __builtin_amdgcn_mfma_f32_16x16x32_f16(ahi0, blo, acc[0][j], 0, 0, 0);
            acc[1][j] = __builtin_amdgcn_mfma_f32_16x16x32_f16(ahi1, blo, acc[1][j], 0, 0, 0);
        }
        __syncthreads();
    }

    ss0 += __shfl_xor(ss0, 16, 64);
    ss0 += __shfl_xor(ss0, 32, 64);
    ss1 += __shfl_xor(ss1, 16, 64);
    ss1 += __shfl_xor(ss1, 32, 64);

    #pragma unroll
    for (int rt = 0; rt < 2; ++rt) {
        float ssv = rt ? ss1 : ss0;
        #pragma unroll
        for (int reg = 0; reg < 4; ++reg) {
            int rc = lg * 4 + reg;
            float xn = sqrtf(__shfl(ssv, rc, 64));
            int row = t0 + wid * 32 + rt * 16 + rc;
            float* orow = OUT + ((size_t)b * BT + row) * BS;
            #pragma unroll
            for (int j = 0; j < NJ; ++j) {
                int col = j * 16 + lr;
                if (col < BS) {
                    float denom = fmaxf(xn * sn_l[col], 1e-8f);
                    orow[col] = acc[rt][j][reg] * __builtin_amdgcn_rcpf(denom);
                }
            }
        }
    }
}

extern "C" void kernel_launch(void* const* d_in, const int* in_sizes, int n_in,
                              void* d_out, int out_size, void* d_ws, size_t ws_size,
                              hipStream_t stream) {
    const float* X   = (const float*)d_in[0];   // [8, 8192, 256] f32
    const float* SPK = (const float*)d_in[1];   // [8, 200, 256] f32
    float* OUT = (float*)d_out;                 // [8, 8192, 200] f32

    if (ws_size >= (size_t)WS_NEED) {
        _Float16* wsH = (_Float16*)d_ws;
        hipLaunchKernelGGL(spk_prep_kernel, dim3(NJ, 8), dim3(256), 0, stream, SPK, wsH);
        hipLaunchKernelGGL(cos_main_kernel, dim3(BT / 128, 8), dim3(256), 0, stream,
                           X, wsH, OUT);
    } else {
        hipLaunchKernelGGL(cos_scorer_kernel, dim3(BT / TM, 8), dim3(256), 0, stream,
                           X, SPK, OUT);
    }
}